// Round 1
// baseline (7104.256 us; speedup 1.0000x reference)
//
#include <hip/hip_runtime.h>
#include <math.h>

#define DIN 32
#define DREL 32
#define DOUT 64
#define NH 8
#define DHH 8
#define CATA 96   // 2*DIN + DREL
#define CATM 64   // DIN + DREL

__device__ __forceinline__ void atomicMaxFloat(float* addr, float val) {
  if (val >= 0.f) atomicMax((int*)addr, __float_as_int(val));
  else            atomicMin((unsigned int*)addr, __float_as_uint(val));
}

__global__ __launch_bounds__(256) void init_amax_kernel(float* __restrict__ amax, int n) {
  int i = blockIdx.x * blockDim.x + threadIdx.x;
  if (i < n) amax[i] = -INFINITY;
}

// hist[t*R + r] += 1 over the E real edges
__global__ __launch_bounds__(256) void hist_kernel(const int* __restrict__ tail_idxs,
                                                   const int* __restrict__ rel_idxs,
                                                   int* __restrict__ hist, int E, int R) {
  int e = blockIdx.x * blockDim.x + threadIdx.x;
  if (e < E) atomicAdd(&hist[tail_idxs[e] * R + rel_idxs[e]], 1);
}

// self_rel[n][d] = sum_r hist[n][r]*emb_rel[r][d] / sum_r hist[n][r]
// thread per (n,d): lanes 0..31 share n -> hist reads broadcast, emb_rel reads coalesced
__global__ __launch_bounds__(256) void selfrel_kernel(const int* __restrict__ hist,
                                                      const float* __restrict__ emb_rel,
                                                      float* __restrict__ self_rel,
                                                      int N, int R) {
  int i = blockIdx.x * blockDim.x + threadIdx.x;
  if (i >= N * DREL) return;
  int n = i >> 5, d = i & 31;
  const int* hrow = hist + (long long)n * R;
  float acc = 0.f;
  int cnt = 0;
  for (int r = 0; r < R; ++r) {
    int c = hrow[r];
    cnt += c;
    acc += (float)c * emb_rel[r * DREL + d];
  }
  self_rel[i] = acc / (float)cnt;
}

// per-edge attention logits + segment max
__global__ __launch_bounds__(256) void attn_kernel(
    const float* __restrict__ emb_ent, const float* __restrict__ emb_rel,
    const float* __restrict__ attn_W, const float* __restrict__ attn_b,
    const float* __restrict__ attn_vec,
    const int* __restrict__ head_idxs, const int* __restrict__ tail_idxs,
    const int* __restrict__ rel_idxs, const float* __restrict__ self_rel,
    float* __restrict__ attn_raw, float* __restrict__ amax, int E, int N) {
  int e = blockIdx.x * blockDim.x + threadIdx.x;
  if (e >= E + N) return;
  int hn, tn;
  const float* relp;
  if (e < E) {
    hn = head_idxs[e];
    tn = tail_idxs[e];
    relp = emb_rel + (long long)rel_idxs[e] * DREL;
  } else {
    hn = tn = e - E;
    relp = self_rel + (long long)(e - E) * DREL;
  }
  float cat[CATA];
  {
    const float4* a = (const float4*)(emb_ent + (long long)tn * DIN);
    const float4* b = (const float4*)(emb_ent + (long long)hn * DIN);
    const float4* c = (const float4*)relp;
#pragma unroll
    for (int q = 0; q < 8; ++q) {
      float4 v = a[q];
      cat[4 * q + 0] = v.x; cat[4 * q + 1] = v.y; cat[4 * q + 2] = v.z; cat[4 * q + 3] = v.w;
    }
#pragma unroll
    for (int q = 0; q < 8; ++q) {
      float4 v = b[q];
      cat[32 + 4 * q + 0] = v.x; cat[32 + 4 * q + 1] = v.y; cat[32 + 4 * q + 2] = v.z; cat[32 + 4 * q + 3] = v.w;
    }
#pragma unroll
    for (int q = 0; q < 8; ++q) {
      float4 v = c[q];
      cat[64 + 4 * q + 0] = v.x; cat[64 + 4 * q + 1] = v.y; cat[64 + 4 * q + 2] = v.z; cat[64 + 4 * q + 3] = v.w;
    }
  }
  float raw[NH];
#pragma unroll
  for (int hh = 0; hh < NH; ++hh) {
    raw[hh] = 0.f;
#pragma unroll 1
    for (int o2 = 0; o2 < DHH; ++o2) {
      int o = hh * DHH + o2;
      float acc = attn_b[o];
      const float* w = attn_W + o * CATA;
#pragma unroll
      for (int k = 0; k < CATA; ++k) acc = fmaf(w[k], cat[k], acc);
      acc = (acc >= 0.f) ? acc : 0.2f * acc;  // leaky_relu 0.2
      raw[hh] = fmaf(acc, attn_vec[o], raw[hh]);
    }
  }
  float* rp = attn_raw + (long long)e * NH;
  float* ap = amax + (long long)tn * NH;
#pragma unroll
  for (int hh = 0; hh < NH; ++hh) {
    rp[hh] = raw[hh];
    atomicMaxFloat(&ap[hh], raw[hh]);
  }
}

// attn_sum[t][h] += exp(raw - amax)
__global__ __launch_bounds__(256) void sum_kernel(
    const int* __restrict__ tail_idxs, const float* __restrict__ attn_raw,
    const float* __restrict__ amax, float* __restrict__ attn_sum, int E, int N) {
  int e = blockIdx.x * blockDim.x + threadIdx.x;
  if (e >= E + N) return;
  int tn = (e < E) ? tail_idxs[e] : (e - E);
  const float* rp = attn_raw + (long long)e * NH;
  const float* ap = amax + (long long)tn * NH;
  float* sp = attn_sum + (long long)tn * NH;
#pragma unroll
  for (int hh = 0; hh < NH; ++hh) atomicAdd(&sp[hh], expf(rp[hh] - ap[hh]));
}

// out[t] += beta * (aggr_W @ [ent_head, rel] + aggr_b)
__global__ __launch_bounds__(256) void agg_kernel(
    const float* __restrict__ emb_ent, const float* __restrict__ emb_rel,
    const float* __restrict__ aggr_W, const float* __restrict__ aggr_b,
    const int* __restrict__ head_idxs, const int* __restrict__ tail_idxs,
    const int* __restrict__ rel_idxs, const float* __restrict__ self_rel,
    const float* __restrict__ attn_raw, const float* __restrict__ amax,
    const float* __restrict__ attn_sum, float* __restrict__ out, int E, int N) {
  int e = blockIdx.x * blockDim.x + threadIdx.x;
  if (e >= E + N) return;
  int hn, tn;
  const float* relp;
  if (e < E) {
    hn = head_idxs[e];
    tn = tail_idxs[e];
    relp = emb_rel + (long long)rel_idxs[e] * DREL;
  } else {
    hn = tn = e - E;
    relp = self_rel + (long long)(e - E) * DREL;
  }
  float cat[CATM];
  {
    const float4* b = (const float4*)(emb_ent + (long long)hn * DIN);
    const float4* c = (const float4*)relp;
#pragma unroll
    for (int q = 0; q < 8; ++q) {
      float4 v = b[q];
      cat[4 * q + 0] = v.x; cat[4 * q + 1] = v.y; cat[4 * q + 2] = v.z; cat[4 * q + 3] = v.w;
    }
#pragma unroll
    for (int q = 0; q < 8; ++q) {
      float4 v = c[q];
      cat[32 + 4 * q + 0] = v.x; cat[32 + 4 * q + 1] = v.y; cat[32 + 4 * q + 2] = v.z; cat[32 + 4 * q + 3] = v.w;
    }
  }
  const float* rp = attn_raw + (long long)e * NH;
  float beta[NH];
#pragma unroll
  for (int hh = 0; hh < NH; ++hh) {
    float m = amax[(long long)tn * NH + hh];
    float s = attn_sum[(long long)tn * NH + hh];
    beta[hh] = expf(rp[hh] - m) / (s + 1e-16f);
  }
  float* op = out + (long long)tn * DOUT;
#pragma unroll
  for (int hh = 0; hh < NH; ++hh) {
#pragma unroll 1
    for (int o2 = 0; o2 < DHH; ++o2) {
      int o = hh * DHH + o2;
      float acc = aggr_b[o];
      const float* w = aggr_W + o * CATM;
#pragma unroll
      for (int k = 0; k < CATM; ++k) acc = fmaf(w[k], cat[k], acc);
      atomicAdd(&op[o], beta[hh] * acc);
    }
  }
}

extern "C" void kernel_launch(void* const* d_in, const int* in_sizes, int n_in,
                              void* d_out, int out_size, void* d_ws, size_t ws_size,
                              hipStream_t stream) {
  const float* emb_ent  = (const float*)d_in[0];
  const float* emb_rel  = (const float*)d_in[1];
  const float* attn_W   = (const float*)d_in[2];
  const float* attn_b   = (const float*)d_in[3];
  const float* attn_vec = (const float*)d_in[4];
  const float* aggr_W   = (const float*)d_in[5];
  const float* aggr_b   = (const float*)d_in[6];
  const int* head_idxs  = (const int*)d_in[7];
  const int* tail_idxs  = (const int*)d_in[8];
  const int* rel_idxs   = (const int*)d_in[9];

  const int N = in_sizes[0] / DIN;
  const int R = in_sizes[1] / DREL;
  const int E = in_sizes[7];
  const int EN = E + N;
  float* out = (float*)d_out;

  // workspace layout
  char* ws = (char*)d_ws;
  size_t off = 0;
  int* hist = (int*)(ws + off);        off += (size_t)N * R * sizeof(int);       // 25.6 MB
  float* self_rel = (float*)(ws + off); off += (size_t)N * DREL * sizeof(float); // 12.8 MB
  float* amax = (float*)(ws + off);     off += (size_t)N * NH * sizeof(float);   // 3.2 MB
  float* attn_sum = (float*)(ws + off); off += (size_t)N * NH * sizeof(float);   // 3.2 MB
  float* attn_raw = (float*)(ws + off); off += (size_t)EN * NH * sizeof(float);  // 54.4 MB

  hipMemsetAsync(hist, 0, (size_t)N * R * sizeof(int), stream);
  hipMemsetAsync(attn_sum, 0, (size_t)N * NH * sizeof(float), stream);
  hipMemsetAsync(out, 0, (size_t)N * DOUT * sizeof(float), stream);
  init_amax_kernel<<<(N * NH + 255) / 256, 256, 0, stream>>>(amax, N * NH);

  hist_kernel<<<(E + 255) / 256, 256, 0, stream>>>(tail_idxs, rel_idxs, hist, E, R);
  selfrel_kernel<<<(N * DREL + 255) / 256, 256, 0, stream>>>(hist, emb_rel, self_rel, N, R);
  attn_kernel<<<(EN + 255) / 256, 256, 0, stream>>>(emb_ent, emb_rel, attn_W, attn_b,
      attn_vec, head_idxs, tail_idxs, rel_idxs, self_rel, attn_raw, amax, E, N);
  sum_kernel<<<(EN + 255) / 256, 256, 0, stream>>>(tail_idxs, attn_raw, amax, attn_sum, E, N);
  agg_kernel<<<(EN + 255) / 256, 256, 0, stream>>>(emb_ent, emb_rel, aggr_W, aggr_b,
      head_idxs, tail_idxs, rel_idxs, self_rel, attn_raw, amax, attn_sum, out, E, N);
}

// Round 2
// 1576.316 us; speedup vs baseline: 4.5069x; 4.5069x over previous
//
#include <hip/hip_runtime.h>
#include <math.h>

#define DIN 32
#define DREL 32
#define DOUT 64
#define NH 8
#define DHH 8
#define CATA 96   // 2*DIN + DREL
#define CATM 64   // DIN + DREL

// ---------------- hist: hist[t*R + r] += 1 over the E real edges ----------------
__global__ __launch_bounds__(256) void hist_kernel(const int* __restrict__ tail_idxs,
                                                   const int* __restrict__ rel_idxs,
                                                   int* __restrict__ hist, int E, int R) {
  int e = blockIdx.x * blockDim.x + threadIdx.x;
  if (e < E) atomicAdd(&hist[tail_idxs[e] * R + rel_idxs[e]], 1);
}

// ---------------- self_rel + deg ----------------
// self_rel[n][d] = sum_r hist[n][r]*emb_rel[r][d] / deg[n];  deg[n] = sum_r hist[n][r]
__global__ __launch_bounds__(256) void selfrel_kernel(const int* __restrict__ hist,
                                                      const float* __restrict__ emb_rel,
                                                      float* __restrict__ self_rel,
                                                      int* __restrict__ deg,
                                                      int N, int R) {
  int i = blockIdx.x * blockDim.x + threadIdx.x;
  if (i >= N * DREL) return;
  int n = i >> 5, d = i & 31;
  const int* hrow = hist + (long long)n * R;
  float acc = 0.f;
  int cnt = 0;
  for (int r = 0; r < R; ++r) {
    int c = hrow[r];
    cnt += c;
    acc += (float)c * emb_rel[r * DREL + d];
  }
  self_rel[i] = acc / (float)cnt;
  if (d == 0) deg[n] = cnt;
}

// ---------------- exclusive scan of (deg[n]+1) -> offs[0..N] (single block) ----------------
#define SCAN_T 256
__global__ __launch_bounds__(SCAN_T) void scan_kernel(const int* __restrict__ deg,
                                                      int* __restrict__ offs, int N, int E) {
  __shared__ int lsum[SCAN_T];
  int tid = threadIdx.x;
  int per = (N + SCAN_T - 1) / SCAN_T;
  int begin = tid * per;
  int finish = begin + per; if (finish > N) finish = N;
  int s = 0;
  for (int i = begin; i < finish; ++i) s += deg[i] + 1;
  lsum[tid] = s;
  __syncthreads();
  int v = s;
  for (int st = 1; st < SCAN_T; st <<= 1) {
    int other = (tid >= st) ? lsum[tid - st] : 0;
    __syncthreads();
    v += other;
    lsum[tid] = v;
    __syncthreads();
  }
  int run = v - s;  // exclusive prefix of this thread's chunk
  for (int i = begin; i < finish; ++i) { offs[i] = run; run += deg[i] + 1; }
  if (tid == 0) offs[N] = E + N;
}

// ---------------- scatter edges into CSR order (self-loop pinned at slot 0) ----------------
__global__ __launch_bounds__(256) void scatter_kernel(const int* __restrict__ tail_idxs,
                                                      const int* __restrict__ offs,
                                                      int* __restrict__ cur,
                                                      int* __restrict__ eidx, int E, int N) {
  int i = blockIdx.x * blockDim.x + threadIdx.x;
  if (i < E) {
    int t = tail_idxs[i];
    int slot = atomicAdd(&cur[t], 1);
    eidx[offs[t] + 1 + slot] = i;
  } else if (i < E + N) {
    int n = i - E;
    eidx[offs[n]] = E + n;
  }
}

// ---------------- attention logits, written in CSR (pos) order, no atomics ----------------
__global__ __launch_bounds__(256) void attn_pos_kernel(
    const float* __restrict__ emb_ent, const float* __restrict__ emb_rel,
    const float* __restrict__ attn_W, const float* __restrict__ attn_b,
    const float* __restrict__ attn_vec,
    const int* __restrict__ head_idxs, const int* __restrict__ tail_idxs,
    const int* __restrict__ rel_idxs, const float* __restrict__ self_rel,
    const int* __restrict__ eidx,
    float* __restrict__ attn_raw, int E, int N) {
  int pos = blockIdx.x * blockDim.x + threadIdx.x;
  if (pos >= E + N) return;
  int eid = eidx[pos];
  int hn, tn;
  const float* relp;
  if (eid < E) {
    hn = head_idxs[eid];
    tn = tail_idxs[eid];
    relp = emb_rel + (long long)rel_idxs[eid] * DREL;
  } else {
    hn = tn = eid - E;
    relp = self_rel + (long long)(eid - E) * DREL;
  }
  float cat[CATA];
  {
    const float4* a = (const float4*)(emb_ent + (long long)tn * DIN);
    const float4* b = (const float4*)(emb_ent + (long long)hn * DIN);
    const float4* c = (const float4*)relp;
#pragma unroll
    for (int q = 0; q < 8; ++q) {
      float4 v = a[q];
      cat[4 * q + 0] = v.x; cat[4 * q + 1] = v.y; cat[4 * q + 2] = v.z; cat[4 * q + 3] = v.w;
    }
#pragma unroll
    for (int q = 0; q < 8; ++q) {
      float4 v = b[q];
      cat[32 + 4 * q + 0] = v.x; cat[32 + 4 * q + 1] = v.y; cat[32 + 4 * q + 2] = v.z; cat[32 + 4 * q + 3] = v.w;
    }
#pragma unroll
    for (int q = 0; q < 8; ++q) {
      float4 v = c[q];
      cat[64 + 4 * q + 0] = v.x; cat[64 + 4 * q + 1] = v.y; cat[64 + 4 * q + 2] = v.z; cat[64 + 4 * q + 3] = v.w;
    }
  }
  float* rp = attn_raw + (long long)pos * NH;
#pragma unroll
  for (int hh = 0; hh < NH; ++hh) {
    float raw = 0.f;
#pragma unroll 1
    for (int o2 = 0; o2 < DHH; ++o2) {
      int o = hh * DHH + o2;
      float acc = attn_b[o];
      const float* w = attn_W + o * CATA;
#pragma unroll
      for (int k = 0; k < CATA; ++k) acc = fmaf(w[k], cat[k], acc);
      acc = (acc >= 0.f) ? acc : 0.2f * acc;  // leaky_relu 0.2
      raw = fmaf(acc, attn_vec[o], raw);
    }
    rp[hh] = raw;
  }
}

// ---------------- fused segment softmax + weighted aggregation, wave per node ----------------
__global__ __launch_bounds__(256) void node_agg_kernel(
    const float* __restrict__ emb_ent, const float* __restrict__ emb_rel,
    const float* __restrict__ aggr_W, const float* __restrict__ aggr_b,
    const int* __restrict__ head_idxs, const int* __restrict__ rel_idxs,
    const float* __restrict__ self_rel,
    const int* __restrict__ eidx, const int* __restrict__ offs,
    const float* __restrict__ attn_raw,
    float* __restrict__ out, int E, int N, int totalWaves) {
  int wid = (blockIdx.x * blockDim.x + threadIdx.x) >> 6;
  int lane = threadIdx.x & 63;
  // this lane owns output channel o = lane; keep aggr_W row in registers
  float w[CATM];
  {
    const float4* wp = (const float4*)(aggr_W + lane * CATM);
#pragma unroll
    for (int q = 0; q < CATM / 4; ++q) {
      float4 v = wp[q];
      w[4 * q + 0] = v.x; w[4 * q + 1] = v.y; w[4 * q + 2] = v.z; w[4 * q + 3] = v.w;
    }
  }
  float bo = aggr_b[lane];
  int j = lane >> 3, h = lane & 7;
  int hsel = lane >> 3;  // head of output channel `lane`

  for (int t = wid; t < N; t += totalWaves) {
    int start = offs[t];
    int end = offs[t + 1];
    int len = end - start;
    // pass 1a: per-head max over segment (lanes (j,h): j strides edges, h = head)
    float m = -INFINITY;
    for (int i = j; i < len; i += 8)
      m = fmaxf(m, attn_raw[(long long)(start + i) * NH + h]);
    m = fmaxf(m, __shfl_xor(m, 8));
    m = fmaxf(m, __shfl_xor(m, 16));
    m = fmaxf(m, __shfl_xor(m, 32));
    // pass 1b: per-head sum of exp
    float s = 0.f;
    for (int i = j; i < len; i += 8)
      s += expf(attn_raw[(long long)(start + i) * NH + h] - m);
    s += __shfl_xor(s, 8);
    s += __shfl_xor(s, 16);
    s += __shfl_xor(s, 32);
    // redistribute per-head (m,s) to output-channel lanes
    float mh = __shfl(m, hsel);
    float inv_s = 1.f / (__shfl(s, hsel) + 1e-16f);

    float acc = 0.f;
    for (int i = 0; i < len; ++i) {
      int pos = start + i;
      int eid = eidx[pos];
      int hn;
      const float* relp;
      if (eid < E) {
        hn = head_idxs[eid];
        relp = emb_rel + (long long)rel_idxs[eid] * DREL;
      } else {
        hn = eid - E;
        relp = self_rel + (long long)(eid - E) * DREL;
      }
      // cooperative gather of cat[64]: lane k holds cat[k]
      float c = (lane < 32) ? emb_ent[(long long)hn * DIN + lane] : relp[lane - 32];
      float dot = bo;
#pragma unroll
      for (int k = 0; k < CATM; ++k) {
        float ck = __uint_as_float(__builtin_amdgcn_readlane(__float_as_uint(c), k));
        dot = fmaf(w[k], ck, dot);
      }
      float val = attn_raw[(long long)pos * NH + hsel];
      float beta = expf(val - mh) * inv_s;
      acc = fmaf(beta, dot, acc);
    }
    out[(long long)t * DOUT + lane] = acc;
  }
}

extern "C" void kernel_launch(void* const* d_in, const int* in_sizes, int n_in,
                              void* d_out, int out_size, void* d_ws, size_t ws_size,
                              hipStream_t stream) {
  const float* emb_ent  = (const float*)d_in[0];
  const float* emb_rel  = (const float*)d_in[1];
  const float* attn_W   = (const float*)d_in[2];
  const float* attn_b   = (const float*)d_in[3];
  const float* attn_vec = (const float*)d_in[4];
  const float* aggr_W   = (const float*)d_in[5];
  const float* aggr_b   = (const float*)d_in[6];
  const int* head_idxs  = (const int*)d_in[7];
  const int* tail_idxs  = (const int*)d_in[8];
  const int* rel_idxs   = (const int*)d_in[9];

  const int N = in_sizes[0] / DIN;
  const int R = in_sizes[1] / DREL;
  const int E = in_sizes[7];
  const int EN = E + N;
  float* out = (float*)d_out;

  // workspace layout (hist region is dead after selfrel_kernel; reuse it for CSR)
  char* ws = (char*)d_ws;
  size_t off = 0;
  int* hist = (int*)(ws + off);                    // N*R ints (25.6 MB)
  int* offs = hist;                                // N+1 ints   } aliased into
  int* cur  = hist + (N + 1);                      // N ints     } hist region
  int* eidx = hist + (2 * N + 1);                  // E+N ints   } after selfrel
  off += (size_t)N * R * sizeof(int);
  float* self_rel = (float*)(ws + off); off += (size_t)N * DREL * sizeof(float);
  int* deg = (int*)(ws + off);          off += (size_t)N * sizeof(int);
  float* attn_raw = (float*)(ws + off); off += (size_t)EN * NH * sizeof(float);

  hipMemsetAsync(hist, 0, (size_t)N * R * sizeof(int), stream);
  hist_kernel<<<(E + 255) / 256, 256, 0, stream>>>(tail_idxs, rel_idxs, hist, E, R);
  selfrel_kernel<<<(N * DREL + 255) / 256, 256, 0, stream>>>(hist, emb_rel, self_rel, deg, N, R);
  // hist region now dead -> becomes offs/cur/eidx
  scan_kernel<<<1, SCAN_T, 0, stream>>>(deg, offs, N, E);
  hipMemsetAsync(cur, 0, (size_t)N * sizeof(int), stream);
  scatter_kernel<<<(EN + 255) / 256, 256, 0, stream>>>(tail_idxs, offs, cur, eidx, E, N);
  attn_pos_kernel<<<(EN + 255) / 256, 256, 0, stream>>>(emb_ent, emb_rel, attn_W, attn_b,
      attn_vec, head_idxs, tail_idxs, rel_idxs, self_rel, eidx, attn_raw, E, N);
  const int NB = 2048;
  node_agg_kernel<<<NB, 256, 0, stream>>>(emb_ent, emb_rel, aggr_W, aggr_b,
      head_idxs, rel_idxs, self_rel, eidx, offs, attn_raw, out, E, N, NB * 4);
}

// Round 3
// 1134.304 us; speedup vs baseline: 6.2631x; 1.3897x over previous
//
#include <hip/hip_runtime.h>
#include <math.h>

#define DIN 32
#define DREL 32
#define DOUT 64
#define NH 8
#define CATA 96   // 2*DIN + DREL
#define CATM 64   // DIN + DREL
#define CAP 64    // per-node edge cache (covers max degree ~50 here; slow path beyond)

__device__ __forceinline__ ushort f2bf(float x) {
  unsigned u = __float_as_uint(x);
  unsigned r = (u + 0x7FFFu + ((u >> 16) & 1u)) >> 16;  // RNE
  return (ushort)r;
}
__device__ __forceinline__ float bf2f(ushort x) {
  return __uint_as_float(((unsigned)x) << 16);
}

// ---------------- hist: hist[t*R + r] += 1 over the E real edges ----------------
__global__ __launch_bounds__(256) void hist_kernel(const int* __restrict__ tail_idxs,
                                                   const int* __restrict__ rel_idxs,
                                                   int* __restrict__ hist, int E, int R) {
  int e = blockIdx.x * blockDim.x + threadIdx.x;
  if (e < E) atomicAdd(&hist[tail_idxs[e] * R + rel_idxs[e]], 1);
}

// ---------------- relation tables: A_rel[r][o], T_rel[r][o] ----------------
__global__ __launch_bounds__(256) void rel_table_kernel(
    const float* __restrict__ emb_rel, const float* __restrict__ attn_W,
    const float* __restrict__ aggr_W,
    float* __restrict__ A_rel, float* __restrict__ T_rel, int R) {
  int i = blockIdx.x * blockDim.x + threadIdx.x;
  if (i >= R * 64) return;
  int r = i >> 6, o = i & 63;
  const float* er = emb_rel + r * DREL;
  float a = 0.f, t = 0.f;
#pragma unroll
  for (int k = 0; k < DREL; ++k) {
    float e = er[k];
    a = fmaf(attn_W[o * CATA + 2 * DIN + k], e, a);
    t = fmaf(aggr_W[o * CATM + DIN + k], e, t);
  }
  A_rel[i] = a;
  T_rel[i] = t;
}

// ---------------- entity tables (bf16) + deg ----------------
// A_tail = W_a[:, :32] @ ent ; A_head = W_a[:, 32:64] @ ent ; M_ent = W_g[:, :32] @ ent
// SA = (hist @ A_rel)/deg ; SM = (hist @ T_rel)/deg  (== projections of self_rel, exactly)
__global__ __launch_bounds__(256) void ent_table_kernel(
    const float* __restrict__ emb_ent, const float* __restrict__ attn_W,
    const float* __restrict__ aggr_W, const int* __restrict__ hist,
    const float* __restrict__ A_rel, const float* __restrict__ T_rel,
    ushort* __restrict__ A_tail, ushort* __restrict__ A_head, ushort* __restrict__ M_ent,
    ushort* __restrict__ SA, ushort* __restrict__ SM,
    int* __restrict__ deg, int N, int R) {
  int i = blockIdx.x * blockDim.x + threadIdx.x;
  if (i >= N * 64) return;
  int n = i >> 6, o = i & 63;
  const float* ent = emb_ent + (size_t)n * DIN;
  const float* wa = attn_W + o * CATA;
  const float* wg = aggr_W + o * CATM;
  float at = 0.f, ah = 0.f, me = 0.f;
#pragma unroll
  for (int k = 0; k < DIN; ++k) {
    float e = ent[k];
    at = fmaf(wa[k], e, at);
    ah = fmaf(wa[DIN + k], e, ah);
    me = fmaf(wg[k], e, me);
  }
  const int* hrow = hist + (size_t)n * R;
  float sa = 0.f, sm = 0.f;
  int cnt = 0;
#pragma unroll 4
  for (int r = 0; r < R; ++r) {
    int c = hrow[r];
    cnt += c;
    float cf = (float)c;
    sa = fmaf(cf, A_rel[(r << 6) + o], sa);
    sm = fmaf(cf, T_rel[(r << 6) + o], sm);
  }
  float inv = 1.f / (float)cnt;
  A_tail[i] = f2bf(at);
  A_head[i] = f2bf(ah);
  M_ent[i] = f2bf(me);
  SA[i] = f2bf(sa * inv);
  SM[i] = f2bf(sm * inv);
  if (o == 0) deg[n] = cnt;
}

// ---------------- exclusive scan of (deg[n]+1) -> offs[0..N] (single block) ----------------
#define SCAN_T 1024
__global__ __launch_bounds__(SCAN_T) void scan_kernel(const int* __restrict__ deg,
                                                      int* __restrict__ offs, int N, int E) {
  __shared__ int lsum[SCAN_T];
  int tid = threadIdx.x;
  int per = (N + SCAN_T - 1) / SCAN_T;
  int begin = tid * per;
  int finish = begin + per; if (finish > N) finish = N;
  int s = 0;
  for (int i = begin; i < finish; ++i) s += deg[i] + 1;
  lsum[tid] = s;
  __syncthreads();
  int v = s;
  for (int st = 1; st < SCAN_T; st <<= 1) {
    int other = (tid >= st) ? lsum[tid - st] : 0;
    __syncthreads();
    v += other;
    lsum[tid] = v;
    __syncthreads();
  }
  int run = v - s;  // exclusive prefix of this thread's chunk
  for (int i = begin; i < finish; ++i) { offs[i] = run; run += deg[i] + 1; }
  if (tid == 0) offs[N] = E + N;
}

// ---------------- scatter edges into CSR order (self-loop pinned at slot 0) ----------------
__global__ __launch_bounds__(256) void scatter_kernel(const int* __restrict__ tail_idxs,
                                                      const int* __restrict__ offs,
                                                      int* __restrict__ cur,
                                                      int* __restrict__ eidx, int E, int N) {
  int i = blockIdx.x * blockDim.x + threadIdx.x;
  if (i < E) {
    int t = tail_idxs[i];
    int slot = atomicAdd(&cur[t], 1);
    eidx[offs[t] + 1 + slot] = i;
  } else if (i < E + N) {
    int n = i - E;
    eidx[offs[n]] = E + n;
  }
}

// per-lane head-group reduce of lrelu(pre)*avec -> raw of this lane's head
__device__ __forceinline__ float edge_reduce(float pre, float avec) {
  float v = fmaxf(pre, 0.2f * pre) * avec;  // leaky_relu(0.2)
  v += __shfl_xor(v, 1);
  v += __shfl_xor(v, 2);
  v += __shfl_xor(v, 4);
  return v;
}

// ---------------- fused attention + segment softmax + aggregation, wave per node --------
__global__ __launch_bounds__(256) void node_agg_kernel(
    const ushort* __restrict__ A_tail, const ushort* __restrict__ A_head,
    const ushort* __restrict__ M_ent, const ushort* __restrict__ SA,
    const ushort* __restrict__ SM,
    const float* __restrict__ A_rel, const float* __restrict__ T_rel,
    const float* __restrict__ attn_b, const float* __restrict__ attn_vec,
    const float* __restrict__ aggr_b,
    const int* __restrict__ head_idxs, const int* __restrict__ rel_idxs,
    const int* __restrict__ eidx, const int* __restrict__ offs,
    float* __restrict__ out, int E, int N, int totalWaves) {
  __shared__ float praw_all[4][CAP * NH];
  float* praw = praw_all[threadIdx.x >> 6];
  int wid = (blockIdx.x * blockDim.x + threadIdx.x) >> 6;
  int lane = threadIdx.x & 63;
  int h = lane >> 3;
  float avec = attn_vec[lane];
  float ab = attn_b[lane];
  float gb = aggr_b[lane];

  for (int t = wid; t < N; t += totalWaves) {
    int start = offs[t];
    int len = offs[t + 1] - start;
    float at = bf2f(A_tail[(size_t)t * 64 + lane]) + ab;
    // preload up to 64 edges' metadata, packed: (hn<<7)|(r<<1)|self
    int eid0 = eidx[start + (lane < len ? lane : 0)];
    int self0 = (eid0 >= E) ? 1 : 0;
    int hn0 = self0 ? t : head_idxs[eid0];
    int r0 = self0 ? 0 : rel_idxs[eid0];
    int meta = (hn0 << 7) | (r0 << 1) | self0;

    int lcap = len < CAP ? len : CAP;
    float m = -INFINITY;
#pragma unroll 2
    for (int i = 0; i < lcap; ++i) {
      int mm = __shfl(meta, i);
      int self = mm & 1, r = (mm >> 1) & 63, hn = mm >> 7;
      float ah = bf2f(A_head[(size_t)hn * 64 + lane]);
      float ar = self ? bf2f(SA[(size_t)t * 64 + lane]) : A_rel[(r << 6) + lane];
      float v = edge_reduce(at + ah + ar, avec);
      m = fmaxf(m, v);
      if ((lane & 7) == 0) praw[i * 8 + h] = v;
    }
    for (int i = CAP; i < len; ++i) {  // rare giant-node path
      int eid = eidx[start + i];
      int self = eid >= E; int hn = self ? t : head_idxs[eid]; int r = self ? 0 : rel_idxs[eid];
      float ah = bf2f(A_head[(size_t)hn * 64 + lane]);
      float ar = self ? bf2f(SA[(size_t)t * 64 + lane]) : A_rel[(r << 6) + lane];
      m = fmaxf(m, edge_reduce(at + ah + ar, avec));
    }

    float s = 0.f;
    if (len <= CAP) {
      for (int i = (lane & 7); i < len; i += 8) s += __expf(praw[i * 8 + h] - m);
      s += __shfl_xor(s, 1); s += __shfl_xor(s, 2); s += __shfl_xor(s, 4);
    } else {
      for (int i = 0; i < len; ++i) {
        float raw;
        if (i < CAP) raw = praw[i * 8 + h];
        else {
          int eid = eidx[start + i];
          int self = eid >= E; int hn = self ? t : head_idxs[eid]; int r = self ? 0 : rel_idxs[eid];
          float ah = bf2f(A_head[(size_t)hn * 64 + lane]);
          float ar = self ? bf2f(SA[(size_t)t * 64 + lane]) : A_rel[(r << 6) + lane];
          raw = edge_reduce(at + ah + ar, avec);
        }
        s += __expf(raw - m);
      }
    }
    float inv_s = 1.f / (s + 1e-16f);

    float acc = 0.f;
#pragma unroll 2
    for (int i = 0; i < lcap; ++i) {
      int mm = __shfl(meta, i);
      int self = mm & 1, r = (mm >> 1) & 63, hn = mm >> 7;
      float me = bf2f(M_ent[(size_t)hn * 64 + lane]);
      float tr = self ? bf2f(SM[(size_t)t * 64 + lane]) : T_rel[(r << 6) + lane];
      float beta = __expf(praw[i * 8 + h] - m) * inv_s;
      acc = fmaf(beta, me + tr, acc);
    }
    for (int i = CAP; i < len; ++i) {  // rare giant-node path
      int eid = eidx[start + i];
      int self = eid >= E; int hn = self ? t : head_idxs[eid]; int r = self ? 0 : rel_idxs[eid];
      float ah = bf2f(A_head[(size_t)hn * 64 + lane]);
      float ar = self ? bf2f(SA[(size_t)t * 64 + lane]) : A_rel[(r << 6) + lane];
      float raw = edge_reduce(at + ah + ar, avec);
      float me = bf2f(M_ent[(size_t)hn * 64 + lane]);
      float tr = self ? bf2f(SM[(size_t)t * 64 + lane]) : T_rel[(r << 6) + lane];
      acc = fmaf(__expf(raw - m) * inv_s, me + tr, acc);
    }
    out[(size_t)t * 64 + lane] = acc + gb;
  }
}

extern "C" void kernel_launch(void* const* d_in, const int* in_sizes, int n_in,
                              void* d_out, int out_size, void* d_ws, size_t ws_size,
                              hipStream_t stream) {
  const float* emb_ent  = (const float*)d_in[0];
  const float* emb_rel  = (const float*)d_in[1];
  const float* attn_W   = (const float*)d_in[2];
  const float* attn_b   = (const float*)d_in[3];
  const float* attn_vec = (const float*)d_in[4];
  const float* aggr_W   = (const float*)d_in[5];
  const float* aggr_b   = (const float*)d_in[6];
  const int* head_idxs  = (const int*)d_in[7];
  const int* tail_idxs  = (const int*)d_in[8];
  const int* rel_idxs   = (const int*)d_in[9];

  const int N = in_sizes[0] / DIN;
  const int R = in_sizes[1] / DREL;
  const int E = in_sizes[7];
  const int EN = E + N;
  float* out = (float*)d_out;

  // workspace layout (region0: hist first, then aliased as offs/cur/eidx after ent_table)
  char* ws = (char*)d_ws;
  size_t off = 0;
  int* region0 = (int*)(ws + off); off += (size_t)N * R * sizeof(int);   // 25.6 MB
  int* hist = region0;
  int* offs = region0;                 // N+1
  int* cur  = region0 + (N + 1);       // N
  int* eidx = region0 + (2 * N + 1);   // E+N   (total 1.9M ints < N*R)
  int* deg = (int*)(ws + off);      off += (size_t)N * sizeof(int);
  ushort* A_tail = (ushort*)(ws + off); off += (size_t)N * 64 * sizeof(ushort);
  ushort* A_head = (ushort*)(ws + off); off += (size_t)N * 64 * sizeof(ushort);
  ushort* M_ent  = (ushort*)(ws + off); off += (size_t)N * 64 * sizeof(ushort);
  ushort* SA     = (ushort*)(ws + off); off += (size_t)N * 64 * sizeof(ushort);
  ushort* SM     = (ushort*)(ws + off); off += (size_t)N * 64 * sizeof(ushort);
  float* A_rel = (float*)(ws + off); off += (size_t)R * 64 * sizeof(float);
  float* T_rel = (float*)(ws + off); off += (size_t)R * 64 * sizeof(float);

  hipMemsetAsync(hist, 0, (size_t)N * R * sizeof(int), stream);
  hist_kernel<<<(E + 255) / 256, 256, 0, stream>>>(tail_idxs, rel_idxs, hist, E, R);
  rel_table_kernel<<<(R * 64 + 255) / 256, 256, 0, stream>>>(emb_rel, attn_W, aggr_W,
                                                             A_rel, T_rel, R);
  ent_table_kernel<<<(N * 64 + 255) / 256, 256, 0, stream>>>(emb_ent, attn_W, aggr_W,
      hist, A_rel, T_rel, A_tail, A_head, M_ent, SA, SM, deg, N, R);
  // hist region now dead -> becomes offs/cur/eidx
  scan_kernel<<<1, SCAN_T, 0, stream>>>(deg, offs, N, E);
  hipMemsetAsync(cur, 0, (size_t)N * sizeof(int), stream);
  scatter_kernel<<<(EN + 255) / 256, 256, 0, stream>>>(tail_idxs, offs, cur, eidx, E, N);
  const int NB = 2048;
  node_agg_kernel<<<NB, 256, 0, stream>>>(A_tail, A_head, M_ent, SA, SM, A_rel, T_rel,
      attn_b, attn_vec, aggr_b, head_idxs, rel_idxs, eidx, offs, out, E, N, NB * 4);
}

// Round 4
// 510.309 us; speedup vs baseline: 13.9215x; 2.2228x over previous
//
#include <hip/hip_runtime.h>
#include <math.h>

#define DIN 32
#define DREL 32
#define DOUT 64
#define NH 8
#define CATA 96   // 2*DIN + DREL
#define CATM 64   // DIN + DREL

__device__ __forceinline__ ushort f2bf(float x) {
  unsigned u = __float_as_uint(x);
  unsigned r = (u + 0x7FFFu + ((u >> 16) & 1u)) >> 16;  // RNE
  return (ushort)r;
}
__device__ __forceinline__ float bf2f(ushort x) {
  return __uint_as_float(((unsigned)x) << 16);
}

// ---------------- deg[t] = # incoming real edges ----------------
__global__ __launch_bounds__(256) void deg_kernel(const int* __restrict__ tail_idxs,
                                                  int* __restrict__ deg, int E) {
  int e = blockIdx.x * blockDim.x + threadIdx.x;
  if (e < E) atomicAdd(&deg[tail_idxs[e]], 1);
}

// ---------------- CSR range allocation: wave prefix + 1 atomic/wave ----------------
__global__ __launch_bounds__(256) void alloc_kernel(const int* __restrict__ deg,
                                                    int* __restrict__ offs,
                                                    int* __restrict__ counter, int N) {
  int t = blockIdx.x * blockDim.x + threadIdx.x;
  int lane = threadIdx.x & 63;
  int d = (t < N) ? deg[t] : 0;
  int incl = d;
#pragma unroll
  for (int st = 1; st < 64; st <<= 1) {
    int v = __shfl_up(incl, st);
    if (lane >= st) incl += v;
  }
  int total = __shfl(incl, 63);
  int base = 0;
  if (lane == 0) base = atomicAdd(counter, total);
  base = __shfl(base, 0);
  if (t < N) offs[t] = base + incl - d;
}

// ---------------- scatter packed (head<<8)|rel into CSR slots ----------------
__global__ __launch_bounds__(256) void scatter_kernel(const int* __restrict__ head_idxs,
                                                      const int* __restrict__ tail_idxs,
                                                      const int* __restrict__ rel_idxs,
                                                      const int* __restrict__ offs,
                                                      int* __restrict__ cur,
                                                      int* __restrict__ emeta, int E) {
  int i = blockIdx.x * blockDim.x + threadIdx.x;
  if (i >= E) return;
  int t = tail_idxs[i];
  int slot = atomicAdd(&cur[t], 1);
  emeta[offs[t] + slot] = (head_idxs[i] << 8) | rel_idxs[i];
}

// ---------------- relation tables: A_rel[r][o], T_rel[r][o] (fp32, L1-resident) ----------
__global__ __launch_bounds__(256) void rel_table_kernel(
    const float* __restrict__ emb_rel, const float* __restrict__ attn_W,
    const float* __restrict__ aggr_W,
    float* __restrict__ A_rel, float* __restrict__ T_rel, int R) {
  int i = blockIdx.x * blockDim.x + threadIdx.x;
  if (i >= R * 64) return;
  int r = i >> 6, o = i & 63;
  const float* er = emb_rel + r * DREL;
  float a = 0.f, t = 0.f;
#pragma unroll
  for (int k = 0; k < DREL; ++k) {
    float e = er[k];
    a = fmaf(attn_W[o * CATA + 2 * DIN + k], e, a);
    t = fmaf(aggr_W[o * CATM + DIN + k], e, t);
  }
  A_rel[i] = a;
  T_rel[i] = t;
}

// ---------------- transpose weight blocks to [k][o] for coalesced reads ----------------
// WT0 = attn_W[:, :32]^T (tail block), WT1 = attn_W[:, 32:64]^T (head), WT2 = aggr_W[:, :32]^T
__global__ __launch_bounds__(256) void wtrans_kernel(const float* __restrict__ attn_W,
                                                     const float* __restrict__ aggr_W,
                                                     float* __restrict__ WT) {
  int i = blockIdx.x * blockDim.x + threadIdx.x;
  if (i >= 3 * 32 * 64) return;
  int sec = i >> 11, k = (i >> 6) & 31, o = i & 63;
  float v;
  if (sec == 0)      v = attn_W[o * CATA + k];
  else if (sec == 1) v = attn_W[o * CATA + DIN + k];
  else               v = aggr_W[o * CATM + k];
  WT[i] = v;
}

// ---------------- entity tables (bf16): A_tail[n][o]; entT[n][o]=A_head, entT[n][64+o]=M_ent
__global__ __launch_bounds__(256) void ent_table_kernel(
    const float* __restrict__ emb_ent, const float* __restrict__ WT,
    ushort* __restrict__ A_tail, ushort* __restrict__ entT, int N) {
  int i = blockIdx.x * blockDim.x + threadIdx.x;
  if (i >= N * 64) return;
  int n = i >> 6, o = i & 63;
  const float* ent = emb_ent + (size_t)n * DIN;
  float ev[DIN];
  {
    const float4* ep = (const float4*)ent;
#pragma unroll
    for (int q = 0; q < DIN / 4; ++q) {
      float4 v = ep[q];
      ev[4 * q + 0] = v.x; ev[4 * q + 1] = v.y; ev[4 * q + 2] = v.z; ev[4 * q + 3] = v.w;
    }
  }
  const float* wt0 = WT + o;
  const float* wt1 = WT + 2048 + o;
  const float* wt2 = WT + 4096 + o;
  float at = 0.f, ah = 0.f, me = 0.f;
#pragma unroll
  for (int k = 0; k < DIN; ++k) {
    float e = ev[k];
    at = fmaf(wt0[k << 6], e, at);
    ah = fmaf(wt1[k << 6], e, ah);
    me = fmaf(wt2[k << 6], e, me);
  }
  A_tail[i] = f2bf(at);
  entT[((size_t)n << 7) + o] = f2bf(ah);
  entT[((size_t)n << 7) + 64 + o] = f2bf(me);
}

// ---------------- fused single-pass online-softmax aggregation, wave per node ----------
__global__ __launch_bounds__(256) void node_agg_kernel(
    const ushort* __restrict__ A_tail, const ushort* __restrict__ entT,
    const float* __restrict__ A_rel, const float* __restrict__ T_rel,
    const float* __restrict__ attn_b, const float* __restrict__ attn_vec,
    const float* __restrict__ aggr_b,
    const int* __restrict__ emeta, const int* __restrict__ offs,
    const int* __restrict__ deg,
    float* __restrict__ out, int N, int totalWaves) {
  int wid = (blockIdx.x * blockDim.x + threadIdx.x) >> 6;
  int lane = threadIdx.x & 63;
  float avec = attn_vec[lane];
  float ab = attn_b[lane];
  float gb = aggr_b[lane];

  for (int t = wid; t < N; t += totalWaves) {
    int start = offs[t];
    int len = deg[t];
    float at = bf2f(A_tail[((size_t)t << 6) + lane]) + ab;
    float m = -INFINITY, s = 0.f, acc = 0.f, suma = 0.f, sumt = 0.f;
    for (int base = 0; base < len; base += 64) {
      int rem = len - base;
      int nch = rem < 64 ? rem : 64;
      int mm_l = emeta[start + base + (lane < nch ? lane : 0)];
#pragma unroll 2
      for (int i = 0; i < nch; ++i) {
        int mm = __shfl(mm_l, i);
        int hn = mm >> 8, r = mm & 255;
        const ushort* ep = entT + ((size_t)hn << 7) + lane;
        float ah = bf2f(ep[0]);
        float me = bf2f(ep[64]);
        float ar = A_rel[(r << 6) + lane];
        float tr = T_rel[(r << 6) + lane];
        suma += ar;
        sumt += tr;
        float pre = at + ah + ar;
        float v = fmaxf(pre, 0.2f * pre) * avec;  // leaky_relu(0.2) * attn_vec
        v += __shfl_xor(v, 1);
        v += __shfl_xor(v, 2);
        v += __shfl_xor(v, 4);                    // per-head raw, replicated in 8-lane group
        float mn = fmaxf(m, v);
        float c = __expf(m - mn);                 // first iter: exp(-inf)=0
        float e = __expf(v - mn);
        s = s * c + e;
        acc = acc * c + e * (me + tr);
        m = mn;
      }
    }
    // self-loop edge: rel part is exactly (sum of incoming A_rel/T_rel rows)/deg
    float invd = 1.f / (float)len;
    const ushort* ep = entT + ((size_t)t << 7) + lane;
    float ah = bf2f(ep[0]);
    float me = bf2f(ep[64]);
    float pre = at + ah + suma * invd;
    float v = fmaxf(pre, 0.2f * pre) * avec;
    v += __shfl_xor(v, 1);
    v += __shfl_xor(v, 2);
    v += __shfl_xor(v, 4);
    float mn = fmaxf(m, v);
    float c = __expf(m - mn);
    float e = __expf(v - mn);
    s = s * c + e;
    acc = acc * c + e * (me + sumt * invd);
    out[((size_t)t << 6) + lane] = acc / (s + 1e-16f) + gb;
  }
}

extern "C" void kernel_launch(void* const* d_in, const int* in_sizes, int n_in,
                              void* d_out, int out_size, void* d_ws, size_t ws_size,
                              hipStream_t stream) {
  const float* emb_ent  = (const float*)d_in[0];
  const float* emb_rel  = (const float*)d_in[1];
  const float* attn_W   = (const float*)d_in[2];
  const float* attn_b   = (const float*)d_in[3];
  const float* attn_vec = (const float*)d_in[4];
  const float* aggr_W   = (const float*)d_in[5];
  const float* aggr_b   = (const float*)d_in[6];
  const int* head_idxs  = (const int*)d_in[7];
  const int* tail_idxs  = (const int*)d_in[8];
  const int* rel_idxs   = (const int*)d_in[9];

  const int N = in_sizes[0] / DIN;
  const int R = in_sizes[1] / DREL;
  const int E = in_sizes[7];
  float* out = (float*)d_out;

  // workspace layout
  char* ws = (char*)d_ws;
  size_t off = 0;
  int* deg     = (int*)(ws + off); off += (size_t)N * sizeof(int);
  int* cur     = (int*)(ws + off); off += (size_t)N * sizeof(int);
  int* counter = (int*)(ws + off); off += sizeof(int);
  int* offs    = (int*)(ws + off); off += (size_t)N * sizeof(int);
  int* emeta   = (int*)(ws + off); off += (size_t)E * sizeof(int);
  ushort* A_tail = (ushort*)(ws + off); off += (size_t)N * 64 * sizeof(ushort);
  ushort* entT   = (ushort*)(ws + off); off += (size_t)N * 128 * sizeof(ushort);
  float* A_rel = (float*)(ws + off); off += (size_t)R * 64 * sizeof(float);
  float* T_rel = (float*)(ws + off); off += (size_t)R * 64 * sizeof(float);
  float* WT    = (float*)(ws + off); off += 3 * 32 * 64 * sizeof(float);

  // deg, cur, counter zeroed in one shot (contiguous)
  hipMemsetAsync(deg, 0, ((size_t)2 * N + 1) * sizeof(int), stream);

  deg_kernel<<<(E + 255) / 256, 256, 0, stream>>>(tail_idxs, deg, E);
  alloc_kernel<<<(N + 255) / 256, 256, 0, stream>>>(deg, offs, counter, N);
  scatter_kernel<<<(E + 255) / 256, 256, 0, stream>>>(head_idxs, tail_idxs, rel_idxs,
                                                      offs, cur, emeta, E);
  rel_table_kernel<<<(R * 64 + 255) / 256, 256, 0, stream>>>(emb_rel, attn_W, aggr_W,
                                                             A_rel, T_rel, R);
  wtrans_kernel<<<(3 * 32 * 64 + 255) / 256, 256, 0, stream>>>(attn_W, aggr_W, WT);
  ent_table_kernel<<<(N * 64 + 255) / 256, 256, 0, stream>>>(emb_ent, WT, A_tail, entT, N);
  const int NB = 2048;
  node_agg_kernel<<<NB, 256, 0, stream>>>(A_tail, entT, A_rel, T_rel,
      attn_b, attn_vec, aggr_b, emeta, offs, deg, out, N, NB * 4);
}

// Round 5
// 467.189 us; speedup vs baseline: 15.2064x; 1.0923x over previous
//
#include <hip/hip_runtime.h>
#include <math.h>

#define DIN 32
#define DREL 32
#define NH 8
#define CATA 96   // 2*DIN + DREL
#define CATM 64   // DIN + DREL
#define LOG2E 1.44269504088896340736f

__device__ __forceinline__ ushort f2bf(float x) {
  unsigned u = __float_as_uint(x);
  return (ushort)((u + 0x7FFFu + ((u >> 16) & 1u)) >> 16);  // RNE
}
__device__ __forceinline__ float bfhi(unsigned v) { return __uint_as_float(v & 0xFFFF0000u); }
__device__ __forceinline__ float bflo(unsigned v) { return __uint_as_float(v << 16); }

// ---------------- deg[t] = # incoming real edges ----------------
__global__ __launch_bounds__(256) void deg_kernel(const int* __restrict__ tail_idxs,
                                                  int* __restrict__ deg, int E) {
  int e = blockIdx.x * blockDim.x + threadIdx.x;
  if (e < E) atomicAdd(&deg[tail_idxs[e]], 1);
}

// ---------------- CSR range allocation: wave prefix + 1 atomic/wave ----------------
__global__ __launch_bounds__(256) void alloc_kernel(const int* __restrict__ deg,
                                                    int* __restrict__ offs,
                                                    int* __restrict__ counter, int N) {
  int t = blockIdx.x * blockDim.x + threadIdx.x;
  int lane = threadIdx.x & 63;
  int d = (t < N) ? deg[t] : 0;
  int incl = d;
#pragma unroll
  for (int st = 1; st < 64; st <<= 1) {
    int v = __shfl_up(incl, st);
    if (lane >= st) incl += v;
  }
  int total = __shfl(incl, 63);
  int base = 0;
  if (lane == 0) base = atomicAdd(counter, total);
  base = __shfl(base, 0);
  if (t < N) offs[t] = base + incl - d;
}

// ---------------- scatter packed (head<<8)|rel; offs[t] becomes segment END ----------
__global__ __launch_bounds__(256) void scatter_kernel(const int* __restrict__ head_idxs,
                                                      const int* __restrict__ tail_idxs,
                                                      const int* __restrict__ rel_idxs,
                                                      int* __restrict__ offs,
                                                      int* __restrict__ emeta, int E) {
  int i = blockIdx.x * blockDim.x + threadIdx.x;
  if (i >= E) return;
  int slot = atomicAdd(&offs[tail_idxs[i]], 1);
  emeta[slot] = (head_idxs[i] << 8) | rel_idxs[i];
}

// ---------------- fused setup: ART[r][o]=(ar,tr) + WT transpose ----------------
__global__ __launch_bounds__(256) void setup_kernel(const float* __restrict__ emb_rel,
                                                    const float* __restrict__ attn_W,
                                                    const float* __restrict__ aggr_W,
                                                    float2* __restrict__ ART,
                                                    float* __restrict__ WT, int R) {
  int i = blockIdx.x * blockDim.x + threadIdx.x;
  int nART = R * 64;
  if (i < nART) {
    int r = i >> 6, o = i & 63;
    const float* er = emb_rel + r * DREL;
    float a = 0.f, t = 0.f;
#pragma unroll
    for (int k = 0; k < DREL; ++k) {
      float e = er[k];
      a = fmaf(attn_W[o * CATA + 2 * DIN + k], e, a);
      t = fmaf(aggr_W[o * CATM + DIN + k], e, t);
    }
    ART[i] = make_float2(a, t);
  } else if (i < nART + 3 * 2048) {
    int j = i - nART;
    int sec = j >> 11, k = (j >> 6) & 31, o = j & 63;
    float v;
    if (sec == 0)      v = attn_W[o * CATA + k];
    else if (sec == 1) v = attn_W[o * CATA + DIN + k];
    else               v = aggr_W[o * CATM + k];
    WT[j] = v;
  }
}

// ---------------- entity tables: wave per node, WT register-resident ----------------
// A_tail[n][o] bf16 ; entT2[n][o] = (A_head_bf16 << 16) | M_ent_bf16
__global__ __launch_bounds__(256) void ent_table_kernel(const float* __restrict__ emb_ent,
                                                        const float* __restrict__ WT,
                                                        ushort* __restrict__ A_tail,
                                                        unsigned* __restrict__ entT2,
                                                        int N, int totalWaves) {
  int wid = __builtin_amdgcn_readfirstlane((blockIdx.x * blockDim.x + threadIdx.x) >> 6);
  int lane = threadIdx.x & 63;
  float w0[DIN], w1[DIN], w2[DIN];
#pragma unroll
  for (int k = 0; k < DIN; ++k) {
    w0[k] = WT[(k << 6) + lane];
    w1[k] = WT[2048 + (k << 6) + lane];
    w2[k] = WT[4096 + (k << 6) + lane];
  }
  for (int n = wid; n < N; n += totalWaves) {
    const float* ent = emb_ent + (size_t)n * DIN;  // wave-uniform -> scalar loads
    float at = 0.f, ah = 0.f, me = 0.f;
#pragma unroll
    for (int k = 0; k < DIN; ++k) {
      float e = ent[k];
      at = fmaf(w0[k], e, at);
      ah = fmaf(w1[k], e, ah);
      me = fmaf(w2[k], e, me);
    }
    A_tail[((size_t)n << 6) + lane] = f2bf(at);
    entT2[((size_t)n << 6) + lane] = ((unsigned)f2bf(ah) << 16) | f2bf(me);
  }
}

// ---------------- fused online-softmax aggregation, wave per node ----------------
__global__ __launch_bounds__(256) void node_agg_kernel(
    const ushort* __restrict__ A_tail, const unsigned* __restrict__ entT2,
    const float2* __restrict__ ART,
    const float* __restrict__ attn_b, const float* __restrict__ attn_vec,
    const float* __restrict__ aggr_b,
    const int* __restrict__ emeta, const int* __restrict__ offs,
    const int* __restrict__ deg,
    float* __restrict__ out, int N, int totalWaves) {
  int wid = __builtin_amdgcn_readfirstlane((blockIdx.x * blockDim.x + threadIdx.x) >> 6);
  int lane = threadIdx.x & 63;
  float avec = attn_vec[lane] * LOG2E;  // logits tracked in log2 domain
  float ab = attn_b[lane];
  float gb = aggr_b[lane];

  for (int t = wid; t < N; t += totalWaves) {
    int len = deg[t];          // scalar
    int start = offs[t] - len; // offs[t] is segment end after scatter
    float at = __uint_as_float(((unsigned)A_tail[((size_t)t << 6) + lane]) << 16) + ab;
    float m = -INFINITY, s = 0.f, acc = 0.f, suma = 0.f, sumt = 0.f;
#pragma unroll 2
    for (int i = 0; i < len; ++i) {
      int mm = emeta[start + i];  // wave-uniform -> s_load
      int hn = mm >> 8, r = mm & 255;
      unsigned pv = entT2[((size_t)hn << 6) + lane];
      float2 rt = ART[(r << 6) + lane];
      suma += rt.x;
      sumt += rt.y;
      float pre = at + bfhi(pv) + rt.x;
      float v = fmaxf(pre, 0.2f * pre) * avec;  // leaky_relu(0.2) * attn_vec * log2e
      v += __shfl_xor(v, 1);
      v += __shfl_xor(v, 2);
      v += __shfl_xor(v, 4);  // per-head raw (log2), replicated in 8-lane group
      if (!__all(v <= m + 11.5416f)) {  // defer-max, THR=8 nats
        float mn = fmaxf(m, v);
        float c = exp2f(m - mn);
        s *= c;
        acc *= c;
        m = mn;
      }
      float e = exp2f(v - m);
      s += e;
      acc = fmaf(e, bflo(pv) + rt.y, acc);
    }
    // self-loop: rel part is exactly (sum of incoming A_rel/T_rel rows)/deg
    float invd = 1.f / (float)len;
    unsigned pv = entT2[((size_t)t << 6) + lane];
    float pre = at + bfhi(pv) + suma * invd;
    float v = fmaxf(pre, 0.2f * pre) * avec;
    v += __shfl_xor(v, 1);
    v += __shfl_xor(v, 2);
    v += __shfl_xor(v, 4);
    float mn = fmaxf(m, v);
    float c = exp2f(m - mn);
    float e = exp2f(v - mn);
    s = s * c + e;
    acc = fmaf(e, bflo(pv) + sumt * invd, acc * c);
    out[((size_t)t << 6) + lane] = acc / (s + 1e-16f) + gb;
  }
}

extern "C" void kernel_launch(void* const* d_in, const int* in_sizes, int n_in,
                              void* d_out, int out_size, void* d_ws, size_t ws_size,
                              hipStream_t stream) {
  const float* emb_ent  = (const float*)d_in[0];
  const float* emb_rel  = (const float*)d_in[1];
  const float* attn_W   = (const float*)d_in[2];
  const float* attn_b   = (const float*)d_in[3];
  const float* attn_vec = (const float*)d_in[4];
  const float* aggr_W   = (const float*)d_in[5];
  const float* aggr_b   = (const float*)d_in[6];
  const int* head_idxs  = (const int*)d_in[7];
  const int* tail_idxs  = (const int*)d_in[8];
  const int* rel_idxs   = (const int*)d_in[9];

  const int N = in_sizes[0] / DIN;
  const int R = in_sizes[1] / DREL;
  const int E = in_sizes[7];
  float* out = (float*)d_out;

  // workspace layout (deg, counter contiguous for one memset)
  char* ws = (char*)d_ws;
  size_t off = 0;
  int* deg     = (int*)(ws + off); off += (size_t)N * sizeof(int);
  int* counter = (int*)(ws + off); off += sizeof(int);
  int* offs    = (int*)(ws + off); off += (size_t)N * sizeof(int);
  int* emeta   = (int*)(ws + off); off += (size_t)E * sizeof(int);
  ushort* A_tail   = (ushort*)(ws + off);   off += (size_t)N * 64 * sizeof(ushort);
  unsigned* entT2  = (unsigned*)(ws + off); off += (size_t)N * 64 * sizeof(unsigned);
  float2* ART = (float2*)(ws + off); off += (size_t)R * 64 * sizeof(float2);
  float* WT   = (float*)(ws + off);  off += 3 * 32 * 64 * sizeof(float);

  hipMemsetAsync(deg, 0, ((size_t)N + 1) * sizeof(int), stream);

  deg_kernel<<<(E + 255) / 256, 256, 0, stream>>>(tail_idxs, deg, E);
  alloc_kernel<<<(N + 255) / 256, 256, 0, stream>>>(deg, offs, counter, N);
  scatter_kernel<<<(E + 255) / 256, 256, 0, stream>>>(head_idxs, tail_idxs, rel_idxs,
                                                      offs, emeta, E);
  setup_kernel<<<(R * 64 + 3 * 2048 + 255) / 256, 256, 0, stream>>>(emb_rel, attn_W, aggr_W,
                                                                    ART, WT, R);
  ent_table_kernel<<<512, 256, 0, stream>>>(emb_ent, WT, A_tail, entT2, N, 512 * 4);
  const int NB = 2048;
  node_agg_kernel<<<NB, 256, 0, stream>>>(A_tail, entT2, ART, attn_b, attn_vec, aggr_b,
                                          emeta, offs, deg, out, N, NB * 4);
}